// Round 1
// baseline (648.863 us; speedup 1.0000x reference)
//
#include <hip/hip_runtime.h>
#include <hip/hip_bf16.h>

// Problem dims (fixed by setup_inputs)
#define BB 128
#define T_ENC 256
#define T_CTX 200
#define E_DIM 256
#define H_DIM 512
#define V_DIM 50000
#define N_OOV 50
#define VEXT  50050
#define FOURH 2048
#define K_GATES 768   // E + H
#define LOGP_SZ (BB * VEXT)          // 6406400
#define OUT_H1_OFF LOGP_SZ
#define OUT_C1_OFF (LOGP_SZ + BB * H_DIM)

typedef __bf16 bf16x8 __attribute__((ext_vector_type(8)));
typedef float  floatx4 __attribute__((ext_vector_type(4)));

__device__ __forceinline__ float wave_sum(float v) {
#pragma unroll
  for (int m = 32; m > 0; m >>= 1) v += __shfl_xor(v, m, 64);
  return v;
}

__device__ __forceinline__ float sigm(float x) { return 1.0f / (1.0f + __expf(-x)); }

// pack 2 fp32 -> packed bf16x2 (RNE)
__device__ __forceinline__ unsigned f2bf2(float a, float b) {
  unsigned ua = __float_as_uint(a), ub = __float_as_uint(b);
  ua = (ua + 0x7FFFu + ((ua >> 16) & 1u)) >> 16;
  ub = (ub + 0x7FFFu + ((ub >> 16) & 1u)) & 0xFFFF0000u;
  return ua | ub;
}

// ---------------- prep: concat weights to bf16 ----------------
__global__ __launch_bounds__(256) void prep_weights(
    const float* __restrict__ W_ih, const float* __restrict__ W_hh,
    const float* __restrict__ attnW, const float* __restrict__ cattnW,
    const float* __restrict__ attnb, const float* __restrict__ cattnb,
    __bf16* __restrict__ Wcat, __bf16* __restrict__ Wattn, float* __restrict__ attnbc) {
  int n = blockIdx.x, tid = threadIdx.x;
  __bf16* wr = Wcat + n * K_GATES;
  wr[tid]       = (__bf16)W_ih[n * E_DIM + tid];
  wr[256 + tid] = (__bf16)W_hh[n * H_DIM + tid];
  wr[512 + tid] = (__bf16)W_hh[n * H_DIM + 256 + tid];
  if (n < 1024) {
    const float* src = (n < 512) ? (attnW + (size_t)n * H_DIM) : (cattnW + (size_t)(n - 512) * H_DIM);
    __bf16* wa = Wattn + n * H_DIM;
    wa[tid]       = (__bf16)src[tid];
    wa[256 + tid] = (__bf16)src[256 + tid];
  }
  if (n < 4) {
    int i = n * 256 + tid;
    attnbc[i] = (i < 512) ? attnb[i] : cattnb[i - 512];
  }
}

// ---------------- prep: embedding gather + A matrix ----------------
__global__ __launch_bounds__(256) void prep_a(
    const int* __restrict__ input, const float* __restrict__ emb_table,
    const float* __restrict__ h0, __bf16* __restrict__ Abuf, float* __restrict__ embf) {
  int b = blockIdx.x, tid = threadIdx.x;
  int tok = input[b];
  float e = emb_table[(size_t)tok * E_DIM + tid];
  embf[b * E_DIM + tid] = e;
  __bf16* ar = Abuf + b * K_GATES;
  ar[tid] = (__bf16)e;
  ar[256 + tid] = (__bf16)h0[b * H_DIM + tid];
  ar[512 + tid] = (__bf16)h0[b * H_DIM + 256 + tid];
}

// ---------------- MFMA GEMM: C(128 x N) = A(128 x K) @ B(N x K)^T + bias ----------------
// A: bf16, pitch K. B: bf16 (BF32=0) or fp32 converted on the fly (BF32=1), pitch K.
// Tile 128x128, BK=64, 4 waves each computing 64x64 via 4x4 MFMA 16x16x32.
template <int BF32>
__global__ __launch_bounds__(256) void gemm_mfma(
    const __bf16* __restrict__ Abf, const void* __restrict__ Bsrc,
    const float* __restrict__ bias, float* __restrict__ C, int N, int K, int ldc) {
  __shared__ __bf16 As[128][72];  // +8 pad
  __shared__ __bf16 Bs[128][72];
  int tid = threadIdx.x;
  int lane = tid & 63, wid = tid >> 6;
  int wm = wid & 1, wn = wid >> 1;
  int n0 = blockIdx.x * 128;

  floatx4 acc[4][4];
#pragma unroll
  for (int i = 0; i < 4; i++)
#pragma unroll
    for (int j = 0; j < 4; j++) acc[i][j] = (floatx4){0.f, 0.f, 0.f, 0.f};

  int arow = tid >> 1, ahalf = tid & 1;  // each thread: 32 elems (64B) of one row

  for (int k0 = 0; k0 < K; k0 += 64) {
    __syncthreads();
    {  // stage A (bf16 -> LDS), 128 rows x 64
      const uint4* s = (const uint4*)(Abf + arow * K + k0 + ahalf * 32);
      uint4* d = (uint4*)&As[arow][ahalf * 32];
      d[0] = s[0]; d[1] = s[1]; d[2] = s[2]; d[3] = s[3];
    }
    {  // stage B
      int gn = n0 + arow; if (gn > N - 1) gn = N - 1;
      if (BF32) {
        const float4* s = (const float4*)((const float*)Bsrc + (size_t)gn * K + k0 + ahalf * 32);
        uint4* d = (uint4*)&Bs[arow][ahalf * 32];
#pragma unroll
        for (int q = 0; q < 4; q++) {
          float4 fa = s[2 * q], fb = s[2 * q + 1];
          uint4 o;
          o.x = f2bf2(fa.x, fa.y); o.y = f2bf2(fa.z, fa.w);
          o.z = f2bf2(fb.x, fb.y); o.w = f2bf2(fb.z, fb.w);
          d[q] = o;
        }
      } else {
        const uint4* s = (const uint4*)((const __bf16*)Bsrc + (size_t)gn * K + k0 + ahalf * 32);
        uint4* d = (uint4*)&Bs[arow][ahalf * 32];
        d[0] = s[0]; d[1] = s[1]; d[2] = s[2]; d[3] = s[3];
      }
    }
    __syncthreads();
#pragma unroll
    for (int kk = 0; kk < 64; kk += 32) {
      int kbase = kk + (lane >> 4) * 8;
      bf16x8 a[4], b[4];
#pragma unroll
      for (int i = 0; i < 4; i++) a[i] = *(const bf16x8*)&As[wm * 64 + i * 16 + (lane & 15)][kbase];
#pragma unroll
      for (int j = 0; j < 4; j++) b[j] = *(const bf16x8*)&Bs[wn * 64 + j * 16 + (lane & 15)][kbase];
#pragma unroll
      for (int i = 0; i < 4; i++)
#pragma unroll
        for (int j = 0; j < 4; j++)
          acc[i][j] = __builtin_amdgcn_mfma_f32_16x16x32_bf16(a[i], b[j], acc[i][j], 0, 0, 0);
    }
  }
  // epilogue: C/D layout col=lane&15, row=(lane>>4)*4+r  [measured m89/m91]
  int cn = lane & 15, cq = lane >> 4;
#pragma unroll
  for (int i = 0; i < 4; i++)
#pragma unroll
    for (int j = 0; j < 4; j++)
#pragma unroll
      for (int r = 0; r < 4; r++) {
        int row = wm * 64 + i * 16 + cq * 4 + r;
        int col = n0 + wn * 64 + j * 16 + cn;
        if (col < N) {
          float v = acc[i][j][r];
          if (bias) v += bias[col];
          C[(size_t)row * ldc + col] = v;
        }
      }
}

// ---------------- LSTM elementwise ----------------
__global__ __launch_bounds__(256) void lstm_kernel(
    const float* __restrict__ gates, const float* __restrict__ b_ih,
    const float* __restrict__ b_hh, const float* __restrict__ c0,
    float* __restrict__ h1_out, float* __restrict__ c1_out, __bf16* __restrict__ h1b) {
  int idx = blockIdx.x * 256 + threadIdx.x;  // 0 .. 65535
  int b = idx >> 9, j = idx & 511;
  const float* g = gates + b * FOURH;
  float iv = g[j]        + b_ih[j]        + b_hh[j];
  float fv = g[512 + j]  + b_ih[512 + j]  + b_hh[512 + j];
  float gv = g[1024 + j] + b_ih[1024 + j] + b_hh[1024 + j];
  float ov = g[1536 + j] + b_ih[1536 + j] + b_hh[1536 + j];
  float c1 = sigm(fv) * c0[idx] + sigm(iv) * tanhf(gv);
  float h1 = sigm(ov) * tanhf(c1);
  h1_out[idx] = h1;
  c1_out[idx] = c1;
  h1b[idx] = (__bf16)h1;
}

// ---------------- attention (enc + ctx-enc in one launch) ----------------
__global__ __launch_bounds__(256) void attn_kernel(
    const float* __restrict__ enc, const float* __restrict__ cenc,
    const float* __restrict__ decbuf, float* __restrict__ ctx,
    float* __restrict__ cctx, float* __restrict__ csc) {
  int which = blockIdx.x >> 7;
  int b = blockIdx.x & 127;
  int T = which ? T_CTX : T_ENC;
  const float* src = which ? (cenc + (size_t)b * T_CTX * H_DIM) : (enc + (size_t)b * T_ENC * H_DIM);
  const float* decp = decbuf + b * 1024 + which * 512;
  float* outp = (which ? cctx : ctx) + b * H_DIM;
  int tid = threadIdx.x, lane = tid & 63, wid = tid >> 6;
  __shared__ float sS[256];
  __shared__ float red[256];
  float4 d0 = *(const float4*)(decp + lane * 8);
  float4 d1 = *(const float4*)(decp + lane * 8 + 4);
  for (int t = wid; t < T; t += 4) {
    const float* row = src + (size_t)t * H_DIM + lane * 8;
    float4 r0 = *(const float4*)row;
    float4 r1 = *(const float4*)(row + 4);
    float p = r0.x * d0.x + r0.y * d0.y + r0.z * d0.z + r0.w * d0.w +
              r1.x * d1.x + r1.y * d1.y + r1.z * d1.z + r1.w * d1.w;
    p = wave_sum(p);
    if (lane == 0) sS[t] = p;
  }
  __syncthreads();
  float x = (tid < T) ? sS[tid] : -1e30f;
  red[tid] = x; __syncthreads();
  for (int s = 128; s; s >>= 1) { if (tid < s) red[tid] = fmaxf(red[tid], red[tid + s]); __syncthreads(); }
  float m = red[0]; __syncthreads();
  float e = (tid < T) ? __expf(x - m) : 0.f;
  red[tid] = e; __syncthreads();
  for (int s = 128; s; s >>= 1) { if (tid < s) red[tid] += red[tid + s]; __syncthreads(); }
  float inv = 1.0f / red[0];
  __syncthreads();
  sS[tid] = e * inv;
  __syncthreads();
  if (which && tid < T_CTX) csc[b * T_CTX + tid] = sS[tid];
  float a0 = 0.f, a1 = 0.f;
#pragma unroll 4
  for (int t = 0; t < T; t++) {
    float s = sS[t];
    const float* row = src + (size_t)t * H_DIM;
    a0 += s * row[tid];
    a1 += s * row[tid + 256];
  }
  outp[tid] = a0;
  outp[tid + 256] = a1;
}

// ---------------- p_gen ----------------
__global__ __launch_bounds__(256) void pgen_kernel(
    const float* __restrict__ ctx, const float* __restrict__ cctx,
    const float* __restrict__ h1f, const float* __restrict__ embf,
    const float* __restrict__ genW, const float* __restrict__ genb,
    const float* __restrict__ sigb, const int* __restrict__ ctx_inp,
    float* __restrict__ pgen_) {
  int wid = threadIdx.x >> 6, lane = threadIdx.x & 63;
  int b = blockIdx.x * 4 + wid;
  float acc = 0.f;
  for (int j = lane; j < 1792; j += 64) {
    float x;
    if (j < 512) x = ctx[b * 512 + j];
    else if (j < 1024) x = cctx[b * 512 + j - 512];
    else if (j < 1536) x = h1f[b * 512 + j - 1024];
    else x = embf[b * 256 + j - 1536];
    acc += x * genW[j];
  }
  acc = wave_sum(acc);
  float cnt = 0.f;
  for (int j = lane; j < T_CTX; j += 64) cnt += (ctx_inp[b * T_CTX + j] > 0) ? 1.f : 0.f;
  cnt = wave_sum(cnt);
  if (lane == 0) {
    float p = sigm(acc + genb[0] + sigb[0]);
    if (cnt == 0.f) p = 1.0f;
    pgen_[b] = p;
  }
}

// ---------------- row softmax stats (online max/sumexp) ----------------
__global__ __launch_bounds__(256) void stats_kernel(
    const float* __restrict__ logits, float* __restrict__ rowm, float* __restrict__ rows_) {
  int b = blockIdx.x, tid = threadIdx.x;
  const float* rowp = logits + (size_t)b * VEXT;
  float m = -1e30f, s = 0.f;
  for (int v = tid; v < V_DIM; v += 256) {
    float x = rowp[v];
    if (x > m) { s = s * __expf(m - x) + 1.0f; m = x; }
    else s += __expf(x - m);
  }
  __shared__ float sm[256], ss[256];
  sm[tid] = m; ss[tid] = s; __syncthreads();
  for (int st = 128; st; st >>= 1) {
    if (tid < st) {
      float m2 = sm[tid + st], s2 = ss[tid + st];
      float mo = fmaxf(sm[tid], m2);
      ss[tid] = ss[tid] * __expf(sm[tid] - mo) + s2 * __expf(m2 - mo);
      sm[tid] = mo;
    }
    __syncthreads();
  }
  if (tid == 0) { rowm[b] = sm[0]; rows_[b] = ss[0]; }
}

// ---------------- final: logp = log(pgen*softmax + (1-pgen)*copy), in-place ----------------
__global__ __launch_bounds__(256) void final_kernel(
    float* __restrict__ out, const int* __restrict__ ctx_inp,
    const float* __restrict__ csc, const float* __restrict__ pgen_,
    const float* __restrict__ rowm, const float* __restrict__ rows_) {
  __shared__ int sidx[T_CTX];
  __shared__ float sval[T_CTX];
  __shared__ int tmpi[T_CTX];
  __shared__ float tmpv[T_CTX];
  int b = blockIdx.x, tid = threadIdx.x;
  if (tid < T_CTX) { tmpi[tid] = ctx_inp[b * T_CTX + tid]; tmpv[tid] = csc[b * T_CTX + tid]; }
  __syncthreads();
  if (tid < T_CTX) {  // rank sort (stable) by index
    int my = tmpi[tid];
    int rank = 0;
    for (int j = 0; j < T_CTX; j++) {
      int oj = tmpi[j];
      rank += (oj < my) || (oj == my && j < tid);
    }
    sidx[rank] = my;
    sval[rank] = tmpv[tid];
  }
  __syncthreads();
  float pg = pgen_[b], m = rowm[b], inv = 1.0f / rows_[b];
  float pc1 = 1.0f - pg;
  float* rowp = out + (size_t)b * VEXT;
  for (int v = tid; v < VEXT; v += 256) {
    float pv = 0.f;
    if (v < V_DIM) pv = __expf(rowp[v] - m) * inv;
    int lo = 0, hi = T_CTX;
    while (lo < hi) { int mid = (lo + hi) >> 1; if (sidx[mid] < v) lo = mid + 1; else hi = mid; }
    float pc = 0.f;
    while (lo < T_CTX && sidx[lo] == v) { pc += sval[lo]; lo++; }
    float prob = pg * pv + pc1 * pc;
    rowp[v] = __logf(fmaxf(prob, 1e-10f));
  }
}

extern "C" void kernel_launch(void* const* d_in, const int* in_sizes, int n_in,
                              void* d_out, int out_size, void* d_ws, size_t ws_size,
                              hipStream_t stream) {
  const int*   input   = (const int*)d_in[0];
  const float* h0      = (const float*)d_in[1];
  const float* c0      = (const float*)d_in[2];
  const float* enc     = (const float*)d_in[3];
  const float* cenc    = (const float*)d_in[4];
  const int*   ctx_inp = (const int*)d_in[5];
  const float* embT    = (const float*)d_in[6];
  const float* W_ih    = (const float*)d_in[7];
  const float* W_hh    = (const float*)d_in[8];
  const float* b_ih    = (const float*)d_in[9];
  const float* b_hh    = (const float*)d_in[10];
  const float* attnW   = (const float*)d_in[11];
  const float* attnb   = (const float*)d_in[12];
  const float* cattnW  = (const float*)d_in[13];
  const float* cattnb  = (const float*)d_in[14];
  const float* genW    = (const float*)d_in[15];
  const float* genb    = (const float*)d_in[16];
  const float* sigb    = (const float*)d_in[17];
  const float* outW    = (const float*)d_in[18];
  const float* outb    = (const float*)d_in[19];

  char* ws = (char*)d_ws;
  __bf16* Wcat   = (__bf16*)(ws + 0);            // 2048*768*2 = 3145728
  __bf16* Wattn  = (__bf16*)(ws + 3145728);      // 1024*512*2 = 1048576
  float*  attnbc = (float*)(ws + 4194304);       // 4096
  __bf16* Abuf   = (__bf16*)(ws + 4198400);      // 128*768*2 = 196608
  float*  embf   = (float*)(ws + 4395008);       // 131072
  float*  gates  = (float*)(ws + 4526080);       // 1048576
  __bf16* h1b    = (__bf16*)(ws + 5574656);      // 131072
  float*  decbuf = (float*)(ws + 5705728);       // 524288
  float*  ctx    = (float*)(ws + 6230016);       // 262144
  float*  cctx   = (float*)(ws + 6492160);       // 262144
  float*  csc    = (float*)(ws + 6754304);       // 102400
  float*  pgenb  = (float*)(ws + 6856704);       // 512
  float*  rowm   = (float*)(ws + 6857216);       // 512
  float*  rows_  = (float*)(ws + 6857728);       // 512

  float* outF = (float*)d_out;
  float* h1_out = outF + OUT_H1_OFF;
  float* c1_out = outF + OUT_C1_OFF;

  prep_weights<<<2048, 256, 0, stream>>>(W_ih, W_hh, attnW, cattnW, attnb, cattnb, Wcat, Wattn, attnbc);
  prep_a<<<128, 256, 0, stream>>>(input, embT, h0, Abuf, embf);
  gemm_mfma<0><<<16, 256, 0, stream>>>(Abuf, Wcat, nullptr, gates, FOURH, K_GATES, FOURH);
  lstm_kernel<<<256, 256, 0, stream>>>(gates, b_ih, b_hh, c0, h1_out, c1_out, h1b);
  gemm_mfma<0><<<8, 256, 0, stream>>>(h1b, Wattn, attnbc, decbuf, 1024, H_DIM, 1024);
  attn_kernel<<<256, 256, 0, stream>>>(enc, cenc, decbuf, ctx, cctx, csc);
  pgen_kernel<<<32, 256, 0, stream>>>(ctx, cctx, h1_out, embf, genW, genb, sigb, ctx_inp, pgenb);
  // logits written into d_out's logp region (ldc = VEXT), then transformed in place
  gemm_mfma<1><<<391, 256, 0, stream>>>(h1b, outW, outb, outF, V_DIM, H_DIM, VEXT);
  stats_kernel<<<128, 256, 0, stream>>>(outF, rowm, rows_);
  final_kernel<<<128, 256, 0, stream>>>(outF, ctx_inp, csc, pgenb, rowm, rows_);
}

// Round 2
// 412.998 us; speedup vs baseline: 1.5711x; 1.5711x over previous
//
#include <hip/hip_runtime.h>
#include <hip/hip_bf16.h>

// Problem dims (fixed by setup_inputs)
#define BB 128
#define T_ENC 256
#define T_CTX 200
#define E_DIM 256
#define H_DIM 512
#define V_DIM 50000
#define N_OOV 50
#define VEXT  50050
#define FOURH 2048
#define K_GATES 768   // E + H
#define LOGP_SZ (BB * VEXT)          // 6406400
#define OUT_H1_OFF LOGP_SZ
#define OUT_C1_OFF (LOGP_SZ + BB * H_DIM)
#define VCHUNK 2048
#define NCHUNK 25     // 25*2048 = 51200 >= VEXT

typedef __bf16 bf16x8 __attribute__((ext_vector_type(8)));
typedef float  floatx4 __attribute__((ext_vector_type(4)));

__device__ __forceinline__ float wave_sum(float v) {
#pragma unroll
  for (int m = 32; m > 0; m >>= 1) v += __shfl_xor(v, m, 64);
  return v;
}

__device__ __forceinline__ float sigm(float x) { return 1.0f / (1.0f + __expf(-x)); }

// pack 2 fp32 -> packed bf16x2 (RNE)
__device__ __forceinline__ unsigned f2bf2(float a, float b) {
  unsigned ua = __float_as_uint(a), ub = __float_as_uint(b);
  ua = (ua + 0x7FFFu + ((ua >> 16) & 1u)) >> 16;
  ub = (ub + 0x7FFFu + ((ub >> 16) & 1u)) & 0xFFFF0000u;
  return ua | ub;
}

// ---------------- prep: concat weights to bf16 ----------------
__global__ __launch_bounds__(256) void prep_weights(
    const float* __restrict__ W_ih, const float* __restrict__ W_hh,
    const float* __restrict__ attnW, const float* __restrict__ cattnW,
    const float* __restrict__ attnb, const float* __restrict__ cattnb,
    __bf16* __restrict__ Wcat, __bf16* __restrict__ Wattn, float* __restrict__ attnbc) {
  int n = blockIdx.x, tid = threadIdx.x;
  __bf16* wr = Wcat + n * K_GATES;
  wr[tid]       = (__bf16)W_ih[n * E_DIM + tid];
  wr[256 + tid] = (__bf16)W_hh[n * H_DIM + tid];
  wr[512 + tid] = (__bf16)W_hh[n * H_DIM + 256 + tid];
  if (n < 1024) {
    const float* src = (n < 512) ? (attnW + (size_t)n * H_DIM) : (cattnW + (size_t)(n - 512) * H_DIM);
    __bf16* wa = Wattn + n * H_DIM;
    wa[tid]       = (__bf16)src[tid];
    wa[256 + tid] = (__bf16)src[256 + tid];
  }
  if (n < 4) {
    int i = n * 256 + tid;
    attnbc[i] = (i < 512) ? attnb[i] : cattnb[i - 512];
  }
}

// ---------------- prep: embedding gather + A matrix ----------------
__global__ __launch_bounds__(256) void prep_a(
    const int* __restrict__ input, const float* __restrict__ emb_table,
    const float* __restrict__ h0, __bf16* __restrict__ Abuf, float* __restrict__ embf) {
  int b = blockIdx.x, tid = threadIdx.x;
  int tok = input[b];
  float e = emb_table[(size_t)tok * E_DIM + tid];
  embf[b * E_DIM + tid] = e;
  __bf16* ar = Abuf + b * K_GATES;
  ar[tid] = (__bf16)e;
  ar[256 + tid] = (__bf16)h0[b * H_DIM + tid];
  ar[512 + tid] = (__bf16)h0[b * H_DIM + 256 + tid];
}

// ---------------- MFMA GEMM: C(128 x N) = A(128 x K) @ B(N x K)^T + bias ----------------
template <int BF32>
__global__ __launch_bounds__(256) void gemm_mfma(
    const __bf16* __restrict__ Abf, const void* __restrict__ Bsrc,
    const float* __restrict__ bias, float* __restrict__ C, int N, int K, int ldc) {
  __shared__ __bf16 As[128][72];  // +8 pad
  __shared__ __bf16 Bs[128][72];
  int tid = threadIdx.x;
  int lane = tid & 63, wid = tid >> 6;
  int wm = wid & 1, wn = wid >> 1;
  int n0 = blockIdx.x * 128;

  floatx4 acc[4][4];
#pragma unroll
  for (int i = 0; i < 4; i++)
#pragma unroll
    for (int j = 0; j < 4; j++) acc[i][j] = (floatx4){0.f, 0.f, 0.f, 0.f};

  int arow = tid >> 1, ahalf = tid & 1;

  for (int k0 = 0; k0 < K; k0 += 64) {
    __syncthreads();
    {  // stage A
      const uint4* s = (const uint4*)(Abf + arow * K + k0 + ahalf * 32);
      uint4* d = (uint4*)&As[arow][ahalf * 32];
      d[0] = s[0]; d[1] = s[1]; d[2] = s[2]; d[3] = s[3];
    }
    {  // stage B
      int gn = n0 + arow; if (gn > N - 1) gn = N - 1;
      if (BF32) {
        const float4* s = (const float4*)((const float*)Bsrc + (size_t)gn * K + k0 + ahalf * 32);
        uint4* d = (uint4*)&Bs[arow][ahalf * 32];
#pragma unroll
        for (int q = 0; q < 4; q++) {
          float4 fa = s[2 * q], fb = s[2 * q + 1];
          uint4 o;
          o.x = f2bf2(fa.x, fa.y); o.y = f2bf2(fa.z, fa.w);
          o.z = f2bf2(fb.x, fb.y); o.w = f2bf2(fb.z, fb.w);
          d[q] = o;
        }
      } else {
        const uint4* s = (const uint4*)((const __bf16*)Bsrc + (size_t)gn * K + k0 + ahalf * 32);
        uint4* d = (uint4*)&Bs[arow][ahalf * 32];
        d[0] = s[0]; d[1] = s[1]; d[2] = s[2]; d[3] = s[3];
      }
    }
    __syncthreads();
#pragma unroll
    for (int kk = 0; kk < 64; kk += 32) {
      int kbase = kk + (lane >> 4) * 8;
      bf16x8 a[4], b[4];
#pragma unroll
      for (int i = 0; i < 4; i++) a[i] = *(const bf16x8*)&As[wm * 64 + i * 16 + (lane & 15)][kbase];
#pragma unroll
      for (int j = 0; j < 4; j++) b[j] = *(const bf16x8*)&Bs[wn * 64 + j * 16 + (lane & 15)][kbase];
#pragma unroll
      for (int i = 0; i < 4; i++)
#pragma unroll
        for (int j = 0; j < 4; j++)
          acc[i][j] = __builtin_amdgcn_mfma_f32_16x16x32_bf16(a[i], b[j], acc[i][j], 0, 0, 0);
    }
  }
  int cn = lane & 15, cq = lane >> 4;
#pragma unroll
  for (int i = 0; i < 4; i++)
#pragma unroll
    for (int j = 0; j < 4; j++)
#pragma unroll
      for (int r = 0; r < 4; r++) {
        int row = wm * 64 + i * 16 + cq * 4 + r;
        int col = n0 + wn * 64 + j * 16 + cn;
        if (col < N) {
          float v = acc[i][j][r];
          if (bias) v += bias[col];
          C[(size_t)row * ldc + col] = v;
        }
      }
}

// ---------------- LSTM elementwise ----------------
__global__ __launch_bounds__(256) void lstm_kernel(
    const float* __restrict__ gates, const float* __restrict__ b_ih,
    const float* __restrict__ b_hh, const float* __restrict__ c0,
    float* __restrict__ h1_out, float* __restrict__ c1_out, __bf16* __restrict__ h1b) {
  int idx = blockIdx.x * 256 + threadIdx.x;
  int b = idx >> 9, j = idx & 511;
  const float* g = gates + b * FOURH;
  float iv = g[j]        + b_ih[j]        + b_hh[j];
  float fv = g[512 + j]  + b_ih[512 + j]  + b_hh[512 + j];
  float gv = g[1024 + j] + b_ih[1024 + j] + b_hh[1024 + j];
  float ov = g[1536 + j] + b_ih[1536 + j] + b_hh[1536 + j];
  float c1 = sigm(fv) * c0[idx] + sigm(iv) * tanhf(gv);
  float h1 = sigm(ov) * tanhf(c1);
  h1_out[idx] = h1;
  c1_out[idx] = c1;
  h1b[idx] = (__bf16)h1;
}

// ---------------- flash attention: one pass over enc rows ----------------
// grid 1024: g = (which*4+chunk)*128 + b. 4 waves, wave-per-t, online softmax.
__global__ __launch_bounds__(256) void flash_attn(
    const float* __restrict__ enc, const float* __restrict__ cenc,
    const float* __restrict__ decbuf, float* __restrict__ opart,
    float2* __restrict__ mlb, float* __restrict__ rawsc) {
  int g = blockIdx.x;
  int b = g & 127;
  int cc = g >> 7;               // 0..7
  int which = cc >> 2, chunk = cc & 3;
  int tchunk = which ? 50 : 64;
  int t0 = chunk * tchunk;
  const float* src = which ? (cenc + (size_t)b * T_CTX * H_DIM) : (enc + (size_t)b * T_ENC * H_DIM);
  const float* decp = decbuf + b * 1024 + which * 512;
  int tid = threadIdx.x, lane = tid & 63, wid = tid >> 6;
  float4 d0 = *(const float4*)(decp + lane * 8);
  float4 d1 = *(const float4*)(decp + lane * 8 + 4);
  float m = -1e30f, l = 0.f;
  float4 o0 = {0.f, 0.f, 0.f, 0.f}, o1 = {0.f, 0.f, 0.f, 0.f};
  for (int t = t0 + wid; t < t0 + tchunk; t += 4) {
    const float* row = src + (size_t)t * H_DIM + lane * 8;
    float4 r0 = *(const float4*)row;
    float4 r1 = *(const float4*)(row + 4);
    float p = r0.x * d0.x + r0.y * d0.y + r0.z * d0.z + r0.w * d0.w +
              r1.x * d1.x + r1.y * d1.y + r1.z * d1.z + r1.w * d1.w;
    p = wave_sum(p);
    if (which && lane == 0) rawsc[b * T_CTX + t] = p;
    float mn = fmaxf(m, p);
    float sc = __expf(m - mn);
    float e  = __expf(p - mn);
    l = l * sc + e;
    o0.x = o0.x * sc + e * r0.x; o0.y = o0.y * sc + e * r0.y;
    o0.z = o0.z * sc + e * r0.z; o0.w = o0.w * sc + e * r0.w;
    o1.x = o1.x * sc + e * r1.x; o1.y = o1.y * sc + e * r1.y;
    o1.z = o1.z * sc + e * r1.z; o1.w = o1.w * sc + e * r1.w;
    m = mn;
  }
  // in-block combine of the 4 wave partials
  __shared__ float so[4][512];
  __shared__ float sml[4][2];
  *(float4*)&so[wid][lane * 8]     = o0;
  *(float4*)&so[wid][lane * 8 + 4] = o1;
  if (lane == 0) { sml[wid][0] = m; sml[wid][1] = l; }
  __syncthreads();
  float M = fmaxf(fmaxf(sml[0][0], sml[1][0]), fmaxf(sml[2][0], sml[3][0]));
  float w0 = __expf(sml[0][0] - M), w1 = __expf(sml[1][0] - M);
  float w2 = __expf(sml[2][0] - M), w3 = __expf(sml[3][0] - M);
  float L = w0 * sml[0][1] + w1 * sml[1][1] + w2 * sml[2][1] + w3 * sml[3][1];
  int h = tid, h2 = tid + 256;
  float O0 = w0 * so[0][h]  + w1 * so[1][h]  + w2 * so[2][h]  + w3 * so[3][h];
  float O1 = w0 * so[0][h2] + w1 * so[1][h2] + w2 * so[2][h2] + w3 * so[3][h2];
  opart[(size_t)g * 512 + h]  = O0;
  opart[(size_t)g * 512 + h2] = O1;
  if (tid == 0) mlb[g] = make_float2(M, L);
}

// ---------------- combine 4 chunk-partials per (b, which) ----------------
__global__ __launch_bounds__(256) void attn_combine(
    const float* __restrict__ opart, const float2* __restrict__ mlb,
    float* __restrict__ ctx, float* __restrict__ cctx,
    float* __restrict__ Mc, float* __restrict__ Lc) {
  int bw = blockIdx.x;           // b + 128*which
  int b = bw & 127, which = bw >> 7;
  int tid = threadIdx.x;
  int g0 = (which * 4) * 128 + b;
  float2 ml0 = mlb[g0], ml1 = mlb[g0 + 128], ml2 = mlb[g0 + 256], ml3 = mlb[g0 + 384];
  float M = fmaxf(fmaxf(ml0.x, ml1.x), fmaxf(ml2.x, ml3.x));
  float w0 = __expf(ml0.x - M), w1 = __expf(ml1.x - M);
  float w2 = __expf(ml2.x - M), w3 = __expf(ml3.x - M);
  float L = w0 * ml0.y + w1 * ml1.y + w2 * ml2.y + w3 * ml3.y;
  float invL = 1.0f / L;
  float s0 = w0 * opart[(size_t)g0 * 512 + tid]       + w1 * opart[(size_t)(g0 + 128) * 512 + tid] +
             w2 * opart[(size_t)(g0 + 256) * 512 + tid] + w3 * opart[(size_t)(g0 + 384) * 512 + tid];
  int t2 = tid + 256;
  float s1 = w0 * opart[(size_t)g0 * 512 + t2]       + w1 * opart[(size_t)(g0 + 128) * 512 + t2] +
             w2 * opart[(size_t)(g0 + 256) * 512 + t2] + w3 * opart[(size_t)(g0 + 384) * 512 + t2];
  float* outp = (which ? cctx : ctx) + b * 512;
  outp[tid] = s0 * invL;
  outp[t2]  = s1 * invL;
  if (which && tid == 0) { Mc[b] = M; Lc[b] = L; }
}

// ---------------- p_gen ----------------
__global__ __launch_bounds__(256) void pgen_kernel(
    const float* __restrict__ ctx, const float* __restrict__ cctx,
    const float* __restrict__ h1f, const float* __restrict__ embf,
    const float* __restrict__ genW, const float* __restrict__ genb,
    const float* __restrict__ sigb, const int* __restrict__ ctx_inp,
    float* __restrict__ pgen_) {
  int wid = threadIdx.x >> 6, lane = threadIdx.x & 63;
  int b = blockIdx.x * 4 + wid;
  float acc = 0.f;
  for (int j = lane; j < 1792; j += 64) {
    float x;
    if (j < 512) x = ctx[b * 512 + j];
    else if (j < 1024) x = cctx[b * 512 + j - 512];
    else if (j < 1536) x = h1f[b * 512 + j - 1024];
    else x = embf[b * 256 + j - 1536];
    acc += x * genW[j];
  }
  acc = wave_sum(acc);
  float cnt = 0.f;
  for (int j = lane; j < T_CTX; j += 64) cnt += (ctx_inp[b * T_CTX + j] > 0) ? 1.f : 0.f;
  cnt = wave_sum(cnt);
  if (lane == 0) {
    float p = sigm(acc + genb[0] + sigb[0]);
    if (cnt == 0.f) p = 1.0f;
    pgen_[b] = p;
  }
}

// ---------------- softmax stats, stage 1: per-chunk partials ----------------
__global__ __launch_bounds__(256) void stats_part(
    const float* __restrict__ logits, float* __restrict__ mpart, float* __restrict__ spart) {
  int bx = blockIdx.x;           // c*128 + b
  int b = bx & 127, c = bx >> 7;
  int tid = threadIdx.x;
  const float* rowp = logits + (size_t)b * VEXT;
  int v0 = c * VCHUNK + tid * 8;
  float m = -1e30f, s = 0.f;
#pragma unroll
  for (int k = 0; k < 4; k++) {
    int v = v0 + 2 * k;
    float2 x = *(const float2*)(rowp + v);   // stays inside d_out even past VEXT
    if (v < V_DIM) {
      float xv = x.x;
      if (xv > m) { s = s * __expf(m - xv) + 1.0f; m = xv; } else s += __expf(xv - m);
    }
    if (v + 1 < V_DIM) {
      float xv = x.y;
      if (xv > m) { s = s * __expf(m - xv) + 1.0f; m = xv; } else s += __expf(xv - m);
    }
  }
  __shared__ float sm[256], ss[256];
  sm[tid] = m; ss[tid] = s; __syncthreads();
  for (int st = 128; st; st >>= 1) {
    if (tid < st) {
      float m2 = sm[tid + st], s2 = ss[tid + st];
      float mo = fmaxf(sm[tid], m2);
      ss[tid] = ss[tid] * __expf(sm[tid] - mo) + s2 * __expf(m2 - mo);
      sm[tid] = mo;
    }
    __syncthreads();
  }
  if (tid == 0) { mpart[bx] = sm[0]; spart[bx] = ss[0]; }
}

// ---------------- softmax stats, stage 2: combine 25 partials per row ----------------
__global__ __launch_bounds__(128) void stats_comb(
    const float* __restrict__ mpart, const float* __restrict__ spart,
    float* __restrict__ rowm, float* __restrict__ rows_) {
  int b = threadIdx.x;  // 128 threads, 1 block
  float m = -1e30f, s = 0.f;
#pragma unroll
  for (int c = 0; c < NCHUNK; c++) {
    float m2 = mpart[c * 128 + b], s2 = spart[c * 128 + b];
    float mo = fmaxf(m, m2);
    s = s * __expf(m - mo) + s2 * __expf(m2 - mo);
    m = mo;
  }
  rowm[b] = m; rows_[b] = s;
}

// ---------------- final: logp = log(pgen*softmax + (1-pgen)*copy), chunked ----------------
__global__ __launch_bounds__(256) void final_kernel(
    float* __restrict__ out, const int* __restrict__ ctx_inp,
    const float* __restrict__ rawsc, const float* __restrict__ pgen_,
    const float* __restrict__ Mc, const float* __restrict__ Lc,
    const float* __restrict__ rowm, const float* __restrict__ rows_) {
  __shared__ float pc[VCHUNK];
  int bx = blockIdx.x;           // c*128 + b
  int b = bx & 127, c = bx >> 7;
  int tid = threadIdx.x;
#pragma unroll
  for (int k = 0; k < 8; k++) pc[tid * 8 + k] = 0.f;
  __syncthreads();
  int v0c = c * VCHUNK;
  if (tid < T_CTX) {
    int idx = ctx_inp[b * T_CTX + tid];
    int rel = idx - v0c;
    if (rel >= 0 && rel < VCHUNK) {
      float val = __expf(rawsc[b * T_CTX + tid] - Mc[b]) / Lc[b];
      atomicAdd(&pc[rel], val);
    }
  }
  __syncthreads();
  float pg = pgen_[b], m = rowm[b], inv = 1.0f / rows_[b], pc1 = 1.0f - pg;
  float* rowp = out + (size_t)b * VEXT;
  int li0 = tid * 8;
#pragma unroll
  for (int k = 0; k < 4; k++) {
    int li = li0 + 2 * k;
    int v = v0c + li;
    float2 x = *(const float2*)(rowp + v);   // in-bounds of d_out buffer even past VEXT
    float pv0 = (v < V_DIM)     ? __expf(x.x - m) * inv : 0.f;
    float pv1 = (v + 1 < V_DIM) ? __expf(x.y - m) * inv : 0.f;
    float r0 = __logf(fmaxf(pg * pv0 + pc1 * pc[li],     1e-10f));
    float r1 = __logf(fmaxf(pg * pv1 + pc1 * pc[li + 1], 1e-10f));
    if (v + 1 < VEXT)      *(float2*)(rowp + v) = make_float2(r0, r1);
    else if (v < VEXT)     rowp[v] = r0;
  }
}

extern "C" void kernel_launch(void* const* d_in, const int* in_sizes, int n_in,
                              void* d_out, int out_size, void* d_ws, size_t ws_size,
                              hipStream_t stream) {
  const int*   input   = (const int*)d_in[0];
  const float* h0      = (const float*)d_in[1];
  const float* c0      = (const float*)d_in[2];
  const float* enc     = (const float*)d_in[3];
  const float* cenc    = (const float*)d_in[4];
  const int*   ctx_inp = (const int*)d_in[5];
  const float* embT    = (const float*)d_in[6];
  const float* W_ih    = (const float*)d_in[7];
  const float* W_hh    = (const float*)d_in[8];
  const float* b_ih    = (const float*)d_in[9];
  const float* b_hh    = (const float*)d_in[10];
  const float* attnW   = (const float*)d_in[11];
  const float* attnb   = (const float*)d_in[12];
  const float* cattnW  = (const float*)d_in[13];
  const float* cattnb  = (const float*)d_in[14];
  const float* genW    = (const float*)d_in[15];
  const float* genb    = (const float*)d_in[16];
  const float* sigb    = (const float*)d_in[17];
  const float* outW    = (const float*)d_in[18];
  const float* outb    = (const float*)d_in[19];

  char* ws = (char*)d_ws;
  __bf16* Wcat   = (__bf16*)(ws + 0);            // 3145728
  __bf16* Wattn  = (__bf16*)(ws + 3145728);      // 1048576
  float*  attnbc = (float*)(ws + 4194304);       // 4096
  __bf16* Abuf   = (__bf16*)(ws + 4198400);      // 196608
  float*  embf   = (float*)(ws + 4395008);       // 131072
  float*  gates  = (float*)(ws + 4526080);       // 1048576
  __bf16* h1b    = (__bf16*)(ws + 5574656);      // 131072
  float*  decbuf = (float*)(ws + 5705728);       // 524288
  float*  opart  = (float*)(ws + 6230016);       // 1024*512*4 = 2097152
  float2* mlb    = (float2*)(ws + 8327168);      // 1024*8 = 8192
  float*  ctx    = (float*)(ws + 8335360);       // 262144
  float*  cctx   = (float*)(ws + 8597504);       // 262144
  float*  rawsc  = (float*)(ws + 8859648);       // 102400
  float*  Mc     = (float*)(ws + 8962048);       // 512
  float*  Lc     = (float*)(ws + 8962560);       // 512
  float*  pgenb  = (float*)(ws + 8963072);       // 512
  float*  mpart  = (float*)(ws + 8963584);       // 3200*4 = 12800
  float*  spart  = (float*)(ws + 8976384);       // 12800
  float*  rowm   = (float*)(ws + 8989184);       // 512
  float*  rows_  = (float*)(ws + 8989696);       // 512

  float* outF = (float*)d_out;
  float* h1_out = outF + OUT_H1_OFF;
  float* c1_out = outF + OUT_C1_OFF;

  prep_weights<<<2048, 256, 0, stream>>>(W_ih, W_hh, attnW, cattnW, attnb, cattnb, Wcat, Wattn, attnbc);
  prep_a<<<128, 256, 0, stream>>>(input, embT, h0, Abuf, embf);
  gemm_mfma<0><<<16, 256, 0, stream>>>(Abuf, Wcat, nullptr, gates, FOURH, K_GATES, FOURH);
  lstm_kernel<<<256, 256, 0, stream>>>(gates, b_ih, b_hh, c0, h1_out, c1_out, h1b);
  // big out-projection GEMM straight into d_out's logp region (ldc = VEXT)
  gemm_mfma<1><<<391, 256, 0, stream>>>(h1b, outW, outb, outF, V_DIM, H_DIM, VEXT);
  stats_part<<<NCHUNK * 128, 256, 0, stream>>>(outF, mpart, spart);
  stats_comb<<<1, 128, 0, stream>>>(mpart, spart, rowm, rows_);
  gemm_mfma<0><<<8, 256, 0, stream>>>(h1b, Wattn, attnbc, decbuf, 1024, H_DIM, 1024);
  flash_attn<<<1024, 256, 0, stream>>>(enc, cenc, decbuf, opart, mlb, rawsc);
  attn_combine<<<256, 256, 0, stream>>>(opart, mlb, ctx, cctx, Mc, Lc);
  pgen_kernel<<<32, 256, 0, stream>>>(ctx, cctx, h1_out, embf, genW, genb, sigb, ctx_inp, pgenb);
  final_kernel<<<NCHUNK * 128, 256, 0, stream>>>(outF, ctx_inp, rawsc, pgenb, Mc, Lc, rowm, rows_);
}

// Round 3
// 392.454 us; speedup vs baseline: 1.6533x; 1.0523x over previous
//
#include <hip/hip_runtime.h>
#include <hip/hip_bf16.h>

// Problem dims (fixed by setup_inputs)
#define BB 128
#define T_ENC 256
#define T_CTX 200
#define E_DIM 256
#define H_DIM 512
#define V_DIM 50000
#define N_OOV 50
#define VEXT  50050
#define FOURH 2048
#define K_GATES 768   // E + H
#define LOGP_SZ (BB * VEXT)          // 6406400
#define OUT_H1_OFF LOGP_SZ
#define OUT_C1_OFF (LOGP_SZ + BB * H_DIM)
#define VCHUNK 2048
#define NCHUNK 25     // 25*2048 = 51200 >= VEXT
#define NBIG 782      // ceil(50000/64)

typedef __bf16 bf16x8 __attribute__((ext_vector_type(8)));
typedef float  floatx4 __attribute__((ext_vector_type(4)));

__device__ __forceinline__ float wave_sum(float v) {
#pragma unroll
  for (int m = 32; m > 0; m >>= 1) v += __shfl_xor(v, m, 64);
  return v;
}

__device__ __forceinline__ float sigm(float x) { return 1.0f / (1.0f + __expf(-x)); }

// pack 2 fp32 -> packed bf16x2 (RNE)
__device__ __forceinline__ unsigned f2bf2(float a, float b) {
  unsigned ua = __float_as_uint(a), ub = __float_as_uint(b);
  ua = (ua + 0x7FFFu + ((ua >> 16) & 1u)) >> 16;
  ub = (ub + 0x7FFFu + ((ub >> 16) & 1u)) & 0xFFFF0000u;
  return ua | ub;
}

// ---------------- prep: weights->bf16 + A matrix, one launch ----------------
__global__ __launch_bounds__(256) void prep_all(
    const float* __restrict__ W_ih, const float* __restrict__ W_hh,
    const float* __restrict__ attnW, const float* __restrict__ cattnW,
    const float* __restrict__ attnb, const float* __restrict__ cattnb,
    const int* __restrict__ input, const float* __restrict__ embT,
    const float* __restrict__ h0,
    __bf16* __restrict__ Wcat, __bf16* __restrict__ Wattn, float* __restrict__ attnbc,
    __bf16* __restrict__ Abuf, float* __restrict__ embf) {
  int n = blockIdx.x, tid = threadIdx.x;
  if (n < 2048) {
    unsigned* wr = (unsigned*)(Wcat + (size_t)n * K_GATES);
    for (int idx = tid; idx < 384; idx += 256) {
      int e0 = idx * 2;
      float2 x = (e0 < 256) ? *(const float2*)(W_ih + (size_t)n * E_DIM + e0)
                            : *(const float2*)(W_hh + (size_t)n * H_DIM + e0 - 256);
      wr[idx] = f2bf2(x.x, x.y);
    }
    if (n < 1024) {
      const float* src = (n < 512) ? (attnW + (size_t)n * H_DIM) : (cattnW + (size_t)(n - 512) * H_DIM);
      unsigned* wa = (unsigned*)(Wattn + (size_t)n * H_DIM);
      float2 x = *(const float2*)(src + tid * 2);
      wa[tid] = f2bf2(x.x, x.y);
    }
    if (n < 4) {
      int i = n * 256 + tid;
      attnbc[i] = (i < 512) ? attnb[i] : cattnb[i - 512];
    }
  } else {
    int b = n - 2048;
    int tok = input[b];
    unsigned* ar = (unsigned*)(Abuf + (size_t)b * K_GATES);
    for (int idx = tid; idx < 384; idx += 256) {
      int e0 = idx * 2;
      float2 x;
      if (e0 < 256) {
        x = *(const float2*)(embT + (size_t)tok * E_DIM + e0);
        *(float2*)(embf + b * E_DIM + e0) = x;
      } else {
        x = *(const float2*)(h0 + (size_t)b * H_DIM + e0 - 256);
      }
      ar[idx] = f2bf2(x.x, x.y);
    }
  }
}

// ---------------- GEMM body: C(128 x N) tile of N=64, reg-prefetch pipeline ----------------
// M=128 (full), per-block N-tile 64, BK=64. 4 waves stacked in M (32 rows each).
// B row-major [N][Kpitch]; BF32=1 converts fp32->bf16 on the fly.
template <int BF32>
__device__ __forceinline__ void gemm64_body(
    const __bf16* __restrict__ Abf, const void* __restrict__ Bsrc,
    const float* __restrict__ bias, float* __restrict__ C,
    int n0, int N, int Koff, int Klen, int Kpitch, int ldc) {
  __shared__ __bf16 As[128][72];
  __shared__ __bf16 Bs[64][72];
  int tid = threadIdx.x, lane = tid & 63, wid = tid >> 6;

  floatx4 acc[2][4];
#pragma unroll
  for (int i = 0; i < 2; i++)
#pragma unroll
    for (int j = 0; j < 4; j++) acc[i][j] = (floatx4){0.f, 0.f, 0.f, 0.f};

  int arow = tid >> 1, ahalf = tid & 1;   // A: 128 rows x 64 bf16, 64 B/thread
  int brow = tid >> 2, bq = tid & 3;      // B: 64 rows x 64, 16 elems/thread
  int gnb = n0 + brow; if (gnb > N - 1) gnb = N - 1;

  const __bf16* abase = Abf + (size_t)arow * Kpitch + Koff + ahalf * 32;
  const float*  bfb = (const float*)Bsrc + (size_t)gnb * Kpitch + Koff + bq * 16;
  const __bf16* bhb = (const __bf16*)Bsrc + (size_t)gnb * Kpitch + Koff + bq * 16;

  uint4 ra[4];
  float4 rbf[4];
  uint4 rbh[2];
  {
    const uint4* s = (const uint4*)abase;
    ra[0] = s[0]; ra[1] = s[1]; ra[2] = s[2]; ra[3] = s[3];
    if (BF32) { const float4* t = (const float4*)bfb; rbf[0] = t[0]; rbf[1] = t[1]; rbf[2] = t[2]; rbf[3] = t[3]; }
    else      { const uint4* t = (const uint4*)bhb;  rbh[0] = t[0]; rbh[1] = t[1]; }
  }

  for (int k0 = 0; k0 < Klen; k0 += 64) {
    __syncthreads();
    { uint4* d = (uint4*)&As[arow][ahalf * 32]; d[0] = ra[0]; d[1] = ra[1]; d[2] = ra[2]; d[3] = ra[3]; }
    if (BF32) {
      uint4 o0, o1;
      o0.x = f2bf2(rbf[0].x, rbf[0].y); o0.y = f2bf2(rbf[0].z, rbf[0].w);
      o0.z = f2bf2(rbf[1].x, rbf[1].y); o0.w = f2bf2(rbf[1].z, rbf[1].w);
      o1.x = f2bf2(rbf[2].x, rbf[2].y); o1.y = f2bf2(rbf[2].z, rbf[2].w);
      o1.z = f2bf2(rbf[3].x, rbf[3].y); o1.w = f2bf2(rbf[3].z, rbf[3].w);
      uint4* d = (uint4*)&Bs[brow][bq * 16]; d[0] = o0; d[1] = o1;
    } else {
      uint4* d = (uint4*)&Bs[brow][bq * 16]; d[0] = rbh[0]; d[1] = rbh[1];
    }
    if (k0 + 64 < Klen) {  // prefetch next K-slab into regs; overlaps with compute below
      const uint4* s = (const uint4*)(abase + k0 + 64);
      ra[0] = s[0]; ra[1] = s[1]; ra[2] = s[2]; ra[3] = s[3];
      if (BF32) { const float4* t = (const float4*)(bfb + k0 + 64); rbf[0] = t[0]; rbf[1] = t[1]; rbf[2] = t[2]; rbf[3] = t[3]; }
      else      { const uint4* t = (const uint4*)(bhb + k0 + 64);  rbh[0] = t[0]; rbh[1] = t[1]; }
    }
    __syncthreads();
#pragma unroll
    for (int kk = 0; kk < 64; kk += 32) {
      int kbase = kk + (lane >> 4) * 8;
      bf16x8 a0 = *(const bf16x8*)&As[wid * 32 + (lane & 15)][kbase];
      bf16x8 a1 = *(const bf16x8*)&As[wid * 32 + 16 + (lane & 15)][kbase];
      bf16x8 bfr[4];
#pragma unroll
      for (int j = 0; j < 4; j++) bfr[j] = *(const bf16x8*)&Bs[j * 16 + (lane & 15)][kbase];
#pragma unroll
      for (int j = 0; j < 4; j++) {
        acc[0][j] = __builtin_amdgcn_mfma_f32_16x16x32_bf16(a0, bfr[j], acc[0][j], 0, 0, 0);
        acc[1][j] = __builtin_amdgcn_mfma_f32_16x16x32_bf16(a1, bfr[j], acc[1][j], 0, 0, 0);
      }
    }
  }
  // C/D layout: col=lane&15, row=(lane>>4)*4+r  [m89/m91]
  int cn = lane & 15, cq = lane >> 4;
#pragma unroll
  for (int i = 0; i < 2; i++)
#pragma unroll
    for (int j = 0; j < 4; j++)
#pragma unroll
      for (int r = 0; r < 4; r++) {
        int row = wid * 32 + i * 16 + cq * 4 + r;
        int col = n0 + j * 16 + cn;
        if (col < N) {
          float v = acc[i][j][r];
          if (bias) v += bias[col];
          C[(size_t)row * ldc + col] = v;
        }
      }
}

// gates GEMM, split-K x2: blocks [kh*32 + nb]
__global__ __launch_bounds__(256) void gates_gemm(
    const __bf16* __restrict__ Abuf, const __bf16* __restrict__ Wcat,
    float* __restrict__ g0, float* __restrict__ g1) {
  int bx = blockIdx.x;
  int kh = bx >> 5, nb = bx & 31;
  gemm64_body<0>(Abuf, Wcat, nullptr, kh ? g1 : g0, nb * 64, FOURH, kh * 384, 384, K_GATES, FOURH);
}

// big out-projection (782 blocks) + attn projection (16 blocks) in one launch
__global__ __launch_bounds__(256) void mega_gemm(
    const __bf16* __restrict__ h1b, const float* __restrict__ outW,
    const float* __restrict__ outb, float* __restrict__ Cbig,
    const __bf16* __restrict__ Wattn, const float* __restrict__ attnbc,
    float* __restrict__ decbuf) {
  int bx = blockIdx.x;
  if (bx < NBIG) gemm64_body<1>(h1b, outW, outb, Cbig, bx * 64, V_DIM, 0, H_DIM, H_DIM, VEXT);
  else           gemm64_body<0>(h1b, Wattn, attnbc, decbuf, (bx - NBIG) * 64, 1024, 0, H_DIM, H_DIM, 1024);
}

// ---------------- LSTM elementwise (sums the two split-K halves) ----------------
__global__ __launch_bounds__(256) void lstm_kernel(
    const float* __restrict__ gA, const float* __restrict__ gB,
    const float* __restrict__ b_ih, const float* __restrict__ b_hh,
    const float* __restrict__ c0,
    float* __restrict__ h1_out, float* __restrict__ c1_out, __bf16* __restrict__ h1b) {
  int idx = blockIdx.x * 256 + threadIdx.x;
  int b = idx >> 9, j = idx & 511;
  const float* ga = gA + b * FOURH;
  const float* gb = gB + b * FOURH;
  float iv = ga[j]        + gb[j]        + b_ih[j]        + b_hh[j];
  float fv = ga[512 + j]  + gb[512 + j]  + b_ih[512 + j]  + b_hh[512 + j];
  float gv = ga[1024 + j] + gb[1024 + j] + b_ih[1024 + j] + b_hh[1024 + j];
  float ov = ga[1536 + j] + gb[1536 + j] + b_ih[1536 + j] + b_hh[1536 + j];
  float c1 = sigm(fv) * c0[idx] + sigm(iv) * tanhf(gv);
  float h1 = sigm(ov) * tanhf(c1);
  h1_out[idx] = h1;
  c1_out[idx] = c1;
  h1b[idx] = (__bf16)h1;
}

// ---------------- flash attention body ----------------
__device__ __forceinline__ void flash_body(
    int g, const float* __restrict__ enc, const float* __restrict__ cenc,
    const float* __restrict__ decbuf, float* __restrict__ opart,
    float2* __restrict__ mlb, float* __restrict__ rawsc) {
  __shared__ float so[4][512];
  __shared__ float sml[4][2];
  int b = g & 127;
  int cc = g >> 7;               // 0..7
  int which = cc >> 2, chunk = cc & 3;
  int tchunk = which ? 50 : 64;
  int t0 = chunk * tchunk;
  const float* src = which ? (cenc + (size_t)b * T_CTX * H_DIM) : (enc + (size_t)b * T_ENC * H_DIM);
  const float* decp = decbuf + b * 1024 + which * 512;
  int tid = threadIdx.x, lane = tid & 63, wid = tid >> 6;
  float4 d0 = *(const float4*)(decp + lane * 8);
  float4 d1 = *(const float4*)(decp + lane * 8 + 4);
  float m = -1e30f, l = 0.f;
  float4 o0 = {0.f, 0.f, 0.f, 0.f}, o1 = {0.f, 0.f, 0.f, 0.f};
  for (int t = t0 + wid; t < t0 + tchunk; t += 4) {
    const float* row = src + (size_t)t * H_DIM + lane * 8;
    float4 r0 = *(const float4*)row;
    float4 r1 = *(const float4*)(row + 4);
    float p = r0.x * d0.x + r0.y * d0.y + r0.z * d0.z + r0.w * d0.w +
              r1.x * d1.x + r1.y * d1.y + r1.z * d1.z + r1.w * d1.w;
    p = wave_sum(p);
    if (which && lane == 0) rawsc[b * T_CTX + t] = p;
    float mn = fmaxf(m, p);
    float sc = __expf(m - mn);
    float e  = __expf(p - mn);
    l = l * sc + e;
    o0.x = o0.x * sc + e * r0.x; o0.y = o0.y * sc + e * r0.y;
    o0.z = o0.z * sc + e * r0.z; o0.w = o0.w * sc + e * r0.w;
    o1.x = o1.x * sc + e * r1.x; o1.y = o1.y * sc + e * r1.y;
    o1.z = o1.z * sc + e * r1.z; o1.w = o1.w * sc + e * r1.w;
    m = mn;
  }
  *(float4*)&so[wid][lane * 8]     = o0;
  *(float4*)&so[wid][lane * 8 + 4] = o1;
  if (lane == 0) { sml[wid][0] = m; sml[wid][1] = l; }
  __syncthreads();
  float M = fmaxf(fmaxf(sml[0][0], sml[1][0]), fmaxf(sml[2][0], sml[3][0]));
  float w0 = __expf(sml[0][0] - M), w1 = __expf(sml[1][0] - M);
  float w2 = __expf(sml[2][0] - M), w3 = __expf(sml[3][0] - M);
  float L = w0 * sml[0][1] + w1 * sml[1][1] + w2 * sml[2][1] + w3 * sml[3][1];
  int h = tid, h2 = tid + 256;
  float O0 = w0 * so[0][h]  + w1 * so[1][h]  + w2 * so[2][h]  + w3 * so[3][h];
  float O1 = w0 * so[0][h2] + w1 * so[1][h2] + w2 * so[2][h2] + w3 * so[3][h2];
  opart[(size_t)g * 512 + h]  = O0;
  opart[(size_t)g * 512 + h2] = O1;
  if (tid == 0) mlb[g] = make_float2(M, L);
}

// ---------------- softmax stats partial body ----------------
__device__ __forceinline__ void stats_body(
    int bx, const float* __restrict__ logits,
    float* __restrict__ mpart, float* __restrict__ spart) {
  __shared__ float sm[256], ss[256];
  int b = bx & 127, c = bx >> 7;
  int tid = threadIdx.x;
  const float* rowp = logits + (size_t)b * VEXT;
  int v0 = c * VCHUNK + tid * 8;
  float m = -1e30f, s = 0.f;
#pragma unroll
  for (int k = 0; k < 4; k++) {
    int v = v0 + 2 * k;
    float2 x = *(const float2*)(rowp + v);   // 8B-aligned (row base is 8B-aligned)
    if (v < V_DIM) {
      float xv = x.x;
      if (xv > m) { s = s * __expf(m - xv) + 1.0f; m = xv; } else s += __expf(xv - m);
    }
    if (v + 1 < V_DIM) {
      float xv = x.y;
      if (xv > m) { s = s * __expf(m - xv) + 1.0f; m = xv; } else s += __expf(xv - m);
    }
  }
  sm[tid] = m; ss[tid] = s; __syncthreads();
  for (int st = 128; st; st >>= 1) {
    if (tid < st) {
      float m2 = sm[tid + st], s2 = ss[tid + st];
      float mo = fmaxf(sm[tid], m2);
      ss[tid] = ss[tid] * __expf(sm[tid] - mo) + s2 * __expf(m2 - mo);
      sm[tid] = mo;
    }
    __syncthreads();
  }
  if (tid == 0) { mpart[bx] = sm[0]; spart[bx] = ss[0]; }
}

// stats (3200 blocks) + flash (1024 blocks) in one launch
__global__ __launch_bounds__(256) void fs_kernel(
    const float* __restrict__ logits, float* __restrict__ mpart, float* __restrict__ spart,
    const float* __restrict__ enc, const float* __restrict__ cenc,
    const float* __restrict__ decbuf, float* __restrict__ opart,
    float2* __restrict__ mlb, float* __restrict__ rawsc) {
  int bx = blockIdx.x;
  if (bx < NCHUNK * 128) stats_body(bx, logits, mpart, spart);
  else flash_body(bx - NCHUNK * 128, enc, cenc, decbuf, opart, mlb, rawsc);
}

// attn_combine (256 blocks) + stats combine (1 block)
__global__ __launch_bounds__(256) void comb_kernel(
    const float* __restrict__ opart, const float2* __restrict__ mlb,
    float* __restrict__ ctx, float* __restrict__ cctx,
    float* __restrict__ Mc, float* __restrict__ Lc,
    const float* __restrict__ mpart, const float* __restrict__ spart,
    float* __restrict__ rowm, float* __restrict__ rows_) {
  int bw = blockIdx.x;
  int tid = threadIdx.x;
  if (bw < 256) {
    int b = bw & 127, which = bw >> 7;
    int g0 = (which * 4) * 128 + b;
    float2 ml0 = mlb[g0], ml1 = mlb[g0 + 128], ml2 = mlb[g0 + 256], ml3 = mlb[g0 + 384];
    float M = fmaxf(fmaxf(ml0.x, ml1.x), fmaxf(ml2.x, ml3.x));
    float w0 = __expf(ml0.x - M), w1 = __expf(ml1.x - M);
    float w2 = __expf(ml2.x - M), w3 = __expf(ml3.x - M);
    float L = w0 * ml0.y + w1 * ml1.y + w2 * ml2.y + w3 * ml3.y;
    float invL = 1.0f / L;
    float s0 = w0 * opart[(size_t)g0 * 512 + tid]         + w1 * opart[(size_t)(g0 + 128) * 512 + tid] +
               w2 * opart[(size_t)(g0 + 256) * 512 + tid] + w3 * opart[(size_t)(g0 + 384) * 512 + tid];
    int t2 = tid + 256;
    float s1 = w0 * opart[(size_t)g0 * 512 + t2]          + w1 * opart[(size_t)(g0 + 128) * 512 + t2] +
               w2 * opart[(size_t)(g0 + 256) * 512 + t2]  + w3 * opart[(size_t)(g0 + 384) * 512 + t2];
    float* outp = (which ? cctx : ctx) + b * 512;
    outp[tid] = s0 * invL;
    outp[t2]  = s1 * invL;
    if (which && tid == 0) { Mc[b] = M; Lc[b] = L; }
  } else if (tid < 128) {
    int b = tid;
    float m = -1e30f, s = 0.f;
#pragma unroll
    for (int c = 0; c < NCHUNK; c++) {
      float m2 = mpart[c * 128 + b], s2 = spart[c * 128 + b];
      float mo = fmaxf(m, m2);
      s = s * __expf(m - mo) + s2 * __expf(m2 - mo);
      m = mo;
    }
    rowm[b] = m; rows_[b] = s;
  }
}

// ---------------- final: p_gen (inline) + logp = log(pgen*softmax + (1-pgen)*copy) ----------------
__global__ __launch_bounds__(256) void final_kernel(
    float* __restrict__ out, const int* __restrict__ ctx_inp,
    const float* __restrict__ rawsc, const float* __restrict__ Mc, const float* __restrict__ Lc,
    const float* __restrict__ rowm, const float* __restrict__ rows_,
    const float* __restrict__ ctx, const float* __restrict__ cctx,
    const float* __restrict__ h1f, const float* __restrict__ embf,
    const float* __restrict__ genW, const float* __restrict__ genb,
    const float* __restrict__ sigb) {
  __shared__ float pc[VCHUNK];
  __shared__ float red8[8];
  int bx = blockIdx.x;           // c*128 + b
  int b = bx & 127, c = bx >> 7;
  int tid = threadIdx.x, lane = tid & 63, wid = tid >> 6;
  int cidx = (tid < T_CTX) ? ctx_inp[b * T_CTX + tid] : 0;
  // inline p_gen: dot(feats, genW) over 1792
  float acc = 0.f;
  for (int j = tid; j < 1792; j += 256) {
    float x;
    if (j < 512) x = ctx[b * 512 + j];
    else if (j < 1024) x = cctx[b * 512 + j - 512];
    else if (j < 1536) x = h1f[b * 512 + j - 1024];
    else x = embf[b * 256 + j - 1536];
    acc += x * genW[j];
  }
  float cnt = (tid < T_CTX && cidx > 0) ? 1.f : 0.f;
  acc = wave_sum(acc); cnt = wave_sum(cnt);
  if (lane == 0) { red8[wid] = acc; red8[4 + wid] = cnt; }
#pragma unroll
  for (int k = 0; k < 8; k++) pc[tid * 8 + k] = 0.f;
  __syncthreads();
  float pg;
  {
    float a = red8[0] + red8[1] + red8[2] + red8[3];
    float cn = red8[4] + red8[5] + red8[6] + red8[7];
    pg = sigm(a + genb[0] + sigb[0]);
    if (cn == 0.f) pg = 1.0f;
  }
  int v0c = c * VCHUNK;
  if (tid < T_CTX) {
    int rel = cidx - v0c;
    if (rel >= 0 && rel < VCHUNK) {
      float val = __expf(rawsc[b * T_CTX + tid] - Mc[b]) / Lc[b];
      atomicAdd(&pc[rel], val);
    }
  }
  __syncthreads();
  float m = rowm[b], inv = 1.0f / rows_[b], pc1 = 1.0f - pg;
  float* rowp = out + (size_t)b * VEXT;
  int li0 = tid * 8;
#pragma unroll
  for (int k = 0; k < 4; k++) {
    int li = li0 + 2 * k;
    int v = v0c + li;
    float2 x = *(const float2*)(rowp + v);   // in-bounds of d_out buffer even past VEXT
    float pv0 = (v < V_DIM)     ? __expf(x.x - m) * inv : 0.f;
    float pv1 = (v + 1 < V_DIM) ? __expf(x.y - m) * inv : 0.f;
    float r0 = __logf(fmaxf(pg * pv0 + pc1 * pc[li],     1e-10f));
    float r1 = __logf(fmaxf(pg * pv1 + pc1 * pc[li + 1], 1e-10f));
    if (v + 1 < VEXT)      *(float2*)(rowp + v) = make_float2(r0, r1);
    else if (v < VEXT)     rowp[v] = r0;
  }
}

extern "C" void kernel_launch(void* const* d_in, const int* in_sizes, int n_in,
                              void* d_out, int out_size, void* d_ws, size_t ws_size,
                              hipStream_t stream) {
  const int*   input   = (const int*)d_in[0];
  const float* h0      = (const float*)d_in[1];
  const float* c0      = (const float*)d_in[2];
  const float* enc     = (const float*)d_in[3];
  const float* cenc    = (const float*)d_in[4];
  const int*   ctx_inp = (const int*)d_in[5];
  const float* embT    = (const float*)d_in[6];
  const float* W_ih    = (const float*)d_in[7];
  const float* W_hh    = (const float*)d_in[8];
  const float* b_ih    = (const float*)d_in[9];
  const float* b_hh    = (const float*)d_in[10];
  const float* attnW   = (const float*)d_in[11];
  const float* attnb   = (const float*)d_in[12];
  const float* cattnW  = (const float*)d_in[13];
  const float* cattnb  = (const float*)d_in[14];
  const float* genW    = (const float*)d_in[15];
  const float* genb    = (const float*)d_in[16];
  const float* sigb    = (const float*)d_in[17];
  const float* outW    = (const float*)d_in[18];
  const float* outb    = (const float*)d_in[19];

  char* ws = (char*)d_ws;
  __bf16* Wcat   = (__bf16*)(ws + 0);            // 3145728
  __bf16* Wattn  = (__bf16*)(ws + 3145728);      // 1048576 -> 4194304
  float*  attnbc = (float*)(ws + 4194304);       // 4096    -> 4198400
  __bf16* Abuf   = (__bf16*)(ws + 4198400);      // 196608  -> 4395008
  float*  embf   = (float*)(ws + 4395008);       // 131072  -> 4526080
  float*  gates  = (float*)(ws + 4526080);       // 1048576 -> 5574656
  float*  gates2 = (float*)(ws + 5574656);       // 1048576 -> 6623232
  __bf16* h1b    = (__bf16*)(ws + 6623232);      // 131072  -> 6754304
  float*  decbuf = (float*)(ws + 6754304);       // 524288  -> 7278592
  float*  opart  = (float*)(ws + 7278592);       // 2097152 -> 9375744
  float2* mlb    = (float2*)(ws + 9375744);      // 8192    -> 9383936
  float*  ctx    = (float*)(ws + 9383936);       // 262144  -> 9646080
  float*  cctx   = (float*)(ws + 9646080);       // 262144  -> 9908224
  float*  rawsc  = (float*)(ws + 9908224);       // 102400  -> 10010624
  float*  Mc     = (float*)(ws + 10010624);      // 512
  float*  Lc     = (float*)(ws + 10011136);      // 512
  float*  mpart  = (float*)(ws + 10011648);      // 12800
  float*  spart  = (float*)(ws + 10024448);      // 12800
  float*  rowm   = (float*)(ws + 10037248);      // 512
  float*  rows_  = (float*)(ws + 10037760);      // 512 -> 10038272 total

  float* outF = (float*)d_out;
  float* h1_out = outF + OUT_H1_OFF;
  float* c1_out = outF + OUT_C1_OFF;

  prep_all<<<2176, 256, 0, stream>>>(W_ih, W_hh, attnW, cattnW, attnb, cattnb,
                                     input, embT, h0, Wcat, Wattn, attnbc, Abuf, embf);
  gates_gemm<<<64, 256, 0, stream>>>(Abuf, Wcat, gates, gates2);
  lstm_kernel<<<256, 256, 0, stream>>>(gates, gates2, b_ih, b_hh, c0, h1_out, c1_out, h1b);
  mega_gemm<<<NBIG + 16, 256, 0, stream>>>(h1b, outW, outb, outF, Wattn, attnbc, decbuf);
  fs_kernel<<<NCHUNK * 128 + 1024, 256, 0, stream>>>(outF, mpart, spart,
                                                     enc, cenc, decbuf, opart, mlb, rawsc);
  comb_kernel<<<257, 256, 0, stream>>>(opart, mlb, ctx, cctx, Mc, Lc, mpart, spart, rowm, rows_);
  final_kernel<<<NCHUNK * 128, 256, 0, stream>>>(outF, ctx_inp, rawsc, Mc, Lc, rowm, rows_,
                                                 ctx, cctx, h1_out, embf, genW, genb, sigb);
}

// Round 4
// 392.088 us; speedup vs baseline: 1.6549x; 1.0009x over previous
//
#include <hip/hip_runtime.h>
#include <hip/hip_bf16.h>

// Problem dims (fixed by setup_inputs)
#define BB 128
#define T_ENC 256
#define T_CTX 200
#define E_DIM 256
#define H_DIM 512
#define V_DIM 50000
#define N_OOV 50
#define VEXT  50050
#define FOURH 2048
#define K_GATES 768   // E + H
#define LOGP_SZ (BB * VEXT)          // 6406400
#define OUT_H1_OFF LOGP_SZ
#define OUT_C1_OFF (LOGP_SZ + BB * H_DIM)
#define VCHUNK 2048
#define NCHUNK 25     // 25*2048 = 51200 >= VEXT
#define NBIG 782      // ceil(50000/64)
#define MSP_PITCH 784 // padded 782

typedef __bf16 bf16x8 __attribute__((ext_vector_type(8)));
typedef float  floatx4 __attribute__((ext_vector_type(4)));

__device__ __forceinline__ float wave_sum(float v) {
#pragma unroll
  for (int m = 32; m > 0; m >>= 1) v += __shfl_xor(v, m, 64);
  return v;
}

__device__ __forceinline__ float sigm(float x) { return 1.0f / (1.0f + __expf(-x)); }

// pack 2 fp32 -> packed bf16x2 (RNE)
__device__ __forceinline__ unsigned f2bf2(float a, float b) {
  unsigned ua = __float_as_uint(a), ub = __float_as_uint(b);
  ua = (ua + 0x7FFFu + ((ua >> 16) & 1u)) >> 16;
  ub = (ub + 0x7FFFu + ((ub >> 16) & 1u)) & 0xFFFF0000u;
  return ua | ub;
}

// ---------------- prep: weights->bf16 + A matrix, one launch ----------------
__global__ __launch_bounds__(256) void prep_all(
    const float* __restrict__ W_ih, const float* __restrict__ W_hh,
    const float* __restrict__ attnW, const float* __restrict__ cattnW,
    const float* __restrict__ attnb, const float* __restrict__ cattnb,
    const int* __restrict__ input, const float* __restrict__ embT,
    const float* __restrict__ h0,
    __bf16* __restrict__ Wcat, __bf16* __restrict__ Wattn, float* __restrict__ attnbc,
    __bf16* __restrict__ Abuf, float* __restrict__ embf) {
  int n = blockIdx.x, tid = threadIdx.x;
  if (n < 2048) {
    unsigned* wr = (unsigned*)(Wcat + (size_t)n * K_GATES);
    for (int idx = tid; idx < 384; idx += 256) {
      int e0 = idx * 2;
      float2 x = (e0 < 256) ? *(const float2*)(W_ih + (size_t)n * E_DIM + e0)
                            : *(const float2*)(W_hh + (size_t)n * H_DIM + e0 - 256);
      wr[idx] = f2bf2(x.x, x.y);
    }
    if (n < 1024) {
      const float* src = (n < 512) ? (attnW + (size_t)n * H_DIM) : (cattnW + (size_t)(n - 512) * H_DIM);
      unsigned* wa = (unsigned*)(Wattn + (size_t)n * H_DIM);
      float2 x = *(const float2*)(src + tid * 2);
      wa[tid] = f2bf2(x.x, x.y);
    }
    if (n < 4) {
      int i = n * 256 + tid;
      attnbc[i] = (i < 512) ? attnb[i] : cattnb[i - 512];
    }
  } else {
    int b = n - 2048;
    int tok = input[b];
    unsigned* ar = (unsigned*)(Abuf + (size_t)b * K_GATES);
    for (int idx = tid; idx < 384; idx += 256) {
      int e0 = idx * 2;
      float2 x;
      if (e0 < 256) {
        x = *(const float2*)(embT + (size_t)tok * E_DIM + e0);
        *(float2*)(embf + b * E_DIM + e0) = x;
      } else {
        x = *(const float2*)(h0 + (size_t)b * H_DIM + e0 - 256);
      }
      ar[idx] = f2bf2(x.x, x.y);
    }
  }
}

// ---------------- GEMM body: C(128 x N) tile of N=64, reg-prefetch pipeline ----------------
// Shared arrays passed in so multiple instantiations in one kernel share LDS.
// STATS=1: also emit per-(row, block) softmax partials (max, sumexp) over cols < N.
template <int BF32, int STATS>
__device__ __forceinline__ void gemm64_body(
    __bf16 (* __restrict__ As)[72], __bf16 (* __restrict__ Bs)[72],
    const __bf16* __restrict__ Abf, const void* __restrict__ Bsrc,
    const float* __restrict__ bias, float* __restrict__ C,
    int n0, int N, int Koff, int Klen, int Kpitch, size_t ldc,
    float2* __restrict__ mspart, int cb) {
  int tid = threadIdx.x, lane = tid & 63, wid = tid >> 6;

  floatx4 acc[2][4];
#pragma unroll
  for (int i = 0; i < 2; i++)
#pragma unroll
    for (int j = 0; j < 4; j++) acc[i][j] = (floatx4){0.f, 0.f, 0.f, 0.f};

  int arow = tid >> 1, ahalf = tid & 1;   // A: 128 rows x 64 bf16, 64 B/thread
  int brow = tid >> 2, bq = tid & 3;      // B: 64 rows x 64, 16 elems/thread
  int gnb = n0 + brow; if (gnb > N - 1) gnb = N - 1;

  const __bf16* abase = Abf + (size_t)arow * Kpitch + Koff + ahalf * 32;
  const float*  bfb = (const float*)Bsrc + (size_t)gnb * Kpitch + Koff + bq * 16;
  const __bf16* bhb = (const __bf16*)Bsrc + (size_t)gnb * Kpitch + Koff + bq * 16;

  uint4 ra[4];
  float4 rbf[4];
  uint4 rbh[2];
  {
    const uint4* s = (const uint4*)abase;
    ra[0] = s[0]; ra[1] = s[1]; ra[2] = s[2]; ra[3] = s[3];
    if (BF32) { const float4* t = (const float4*)bfb; rbf[0] = t[0]; rbf[1] = t[1]; rbf[2] = t[2]; rbf[3] = t[3]; }
    else      { const uint4* t = (const uint4*)bhb;  rbh[0] = t[0]; rbh[1] = t[1]; }
  }

  for (int k0 = 0; k0 < Klen; k0 += 64) {
    __syncthreads();
    { uint4* d = (uint4*)&As[arow][ahalf * 32]; d[0] = ra[0]; d[1] = ra[1]; d[2] = ra[2]; d[3] = ra[3]; }
    if (BF32) {
      uint4 o0, o1;
      o0.x = f2bf2(rbf[0].x, rbf[0].y); o0.y = f2bf2(rbf[0].z, rbf[0].w);
      o0.z = f2bf2(rbf[1].x, rbf[1].y); o0.w = f2bf2(rbf[1].z, rbf[1].w);
      o1.x = f2bf2(rbf[2].x, rbf[2].y); o1.y = f2bf2(rbf[2].z, rbf[2].w);
      o1.z = f2bf2(rbf[3].x, rbf[3].y); o1.w = f2bf2(rbf[3].z, rbf[3].w);
      uint4* d = (uint4*)&Bs[brow][bq * 16]; d[0] = o0; d[1] = o1;
    } else {
      uint4* d = (uint4*)&Bs[brow][bq * 16]; d[0] = rbh[0]; d[1] = rbh[1];
    }
    if (k0 + 64 < Klen) {  // prefetch next K-slab into regs; stays in flight through the MFMA block
      const uint4* s = (const uint4*)(abase + k0 + 64);
      ra[0] = s[0]; ra[1] = s[1]; ra[2] = s[2]; ra[3] = s[3];
      if (BF32) { const float4* t = (const float4*)(bfb + k0 + 64); rbf[0] = t[0]; rbf[1] = t[1]; rbf[2] = t[2]; rbf[3] = t[3]; }
      else      { const uint4* t = (const uint4*)(bhb + k0 + 64);  rbh[0] = t[0]; rbh[1] = t[1]; }
    }
    __syncthreads();
#pragma unroll
    for (int kk = 0; kk < 64; kk += 32) {
      int kbase = kk + (lane >> 4) * 8;
      bf16x8 a0 = *(const bf16x8*)&As[wid * 32 + (lane & 15)][kbase];
      bf16x8 a1 = *(const bf16x8*)&As[wid * 32 + 16 + (lane & 15)][kbase];
      bf16x8 bfr[4];
#pragma unroll
      for (int j = 0; j < 4; j++) bfr[j] = *(const bf16x8*)&Bs[j * 16 + (lane & 15)][kbase];
#pragma unroll
      for (int j = 0; j < 4; j++) {
        acc[0][j] = __builtin_amdgcn_mfma_f32_16x16x32_bf16(a0, bfr[j], acc[0][j], 0, 0, 0);
        acc[1][j] = __builtin_amdgcn_mfma_f32_16x16x32_bf16(a1, bfr[j], acc[1][j], 0, 0, 0);
      }
    }
  }
  // C/D layout: col=lane&15, row=(lane>>4)*4+r  [m89/m91]
  int cn = lane & 15, cq = lane >> 4;
#pragma unroll
  for (int i = 0; i < 2; i++)
#pragma unroll
    for (int j = 0; j < 4; j++)
#pragma unroll
      for (int r = 0; r < 4; r++) {
        int row = wid * 32 + i * 16 + cq * 4 + r;
        int col = n0 + j * 16 + cn;
        if (col < N) {
          float v = acc[i][j][r];
          if (bias) v += bias[col];
          C[(size_t)row * ldc + col] = v;
        }
      }
  if (STATS) {
    // per-row softmax partials over this block's 64 cols (valid cols only)
#pragma unroll
    for (int i = 0; i < 2; i++)
#pragma unroll
      for (int r = 0; r < 4; r++) {
        int row = wid * 32 + i * 16 + cq * 4 + r;
        float v[4]; float mx = -1e30f;
#pragma unroll
        for (int j = 0; j < 4; j++) {
          int col = n0 + j * 16 + cn;
          float x = acc[i][j][r] + bias[col < N ? col : N - 1];
          v[j] = (col < N) ? x : -1e30f;
          mx = fmaxf(mx, v[j]);
        }
#pragma unroll
        for (int mk = 1; mk <= 8; mk <<= 1) mx = fmaxf(mx, __shfl_xor(mx, mk, 64));
        float s = 0.f;
#pragma unroll
        for (int j = 0; j < 4; j++) s += (v[j] > -1e29f) ? __expf(v[j] - mx) : 0.f;
#pragma unroll
        for (int mk = 1; mk <= 8; mk <<= 1) s += __shfl_xor(s, mk, 64);
        if (cn == 0) mspart[(size_t)row * MSP_PITCH + cb] = make_float2(mx, s);
      }
  }
}

// gates GEMM, split-K x2: blocks [kh*32 + nb]
__global__ __launch_bounds__(256) void gates_gemm(
    const __bf16* __restrict__ Abuf, const __bf16* __restrict__ Wcat,
    float* __restrict__ g0, float* __restrict__ g1) {
  __shared__ __bf16 As[128][72];
  __shared__ __bf16 Bs[64][72];
  int bx = blockIdx.x;
  int kh = bx >> 5, nb = bx & 31;
  gemm64_body<0, 0>(As, Bs, Abuf, Wcat, nullptr, kh ? g1 : g0, nb * 64, FOURH,
                    kh * 384, 384, K_GATES, FOURH, nullptr, 0);
}

// big out-projection (782 blocks, + fused softmax partials) + attn projection (16 blocks)
__global__ __launch_bounds__(256) void mega_gemm(
    const __bf16* __restrict__ h1b, const float* __restrict__ outW,
    const float* __restrict__ outb, float* __restrict__ logits, size_t lpitch,
    const __bf16* __restrict__ Wattn, const float* __restrict__ attnbc,
    float* __restrict__ decbuf, float2* __restrict__ mspart) {
  __shared__ __bf16 As[128][72];
  __shared__ __bf16 Bs[64][72];
  int bx = blockIdx.x;
  if (bx < NBIG)
    gemm64_body<1, 1>(As, Bs, h1b, outW, outb, logits, bx * 64, V_DIM,
                      0, H_DIM, H_DIM, lpitch, mspart, bx);
  else
    gemm64_body<0, 0>(As, Bs, h1b, Wattn, attnbc, decbuf, (bx - NBIG) * 64, 1024,
                      0, H_DIM, H_DIM, 1024, nullptr, 0);
}

// ---------------- LSTM elementwise (sums the two split-K halves) ----------------
__global__ __launch_bounds__(256) void lstm_kernel(
    const float* __restrict__ gA, const float* __restrict__ gB,
    const float* __restrict__ b_ih, const float* __restrict__ b_hh,
    const float* __restrict__ c0,
    float* __restrict__ h1_out, float* __restrict__ c1_out, __bf16* __restrict__ h1b) {
  int idx = blockIdx.x * 256 + threadIdx.x;
  int b = idx >> 9, j = idx & 511;
  const float* ga = gA + b * FOURH;
  const float* gb = gB + b * FOURH;
  float iv = ga[j]        + gb[j]        + b_ih[j]        + b_hh[j];
  float fv = ga[512 + j]  + gb[512 + j]  + b_ih[512 + j]  + b_hh[512 + j];
  float gv = ga[1024 + j] + gb[1024 + j] + b_ih[1024 + j] + b_hh[1024 + j];
  float ov = ga[1536 + j] + gb[1536 + j] + b_ih[1536 + j] + b_hh[1536 + j];
  float c1 = sigm(fv) * c0[idx] + sigm(iv) * tanhf(gv);
  float h1 = sigm(ov) * tanhf(c1);
  h1_out[idx] = h1;
  c1_out[idx] = c1;
  h1b[idx] = (__bf16)h1;
}

// ---------------- flash attention (1024 blocks) ----------------
__global__ __launch_bounds__(256) void flash_kernel(
    const float* __restrict__ enc, const float* __restrict__ cenc,
    const float* __restrict__ decbuf, float* __restrict__ opart,
    float2* __restrict__ mlb, float* __restrict__ rawsc) {
  __shared__ float so[4][512];
  __shared__ float sml[4][2];
  int g = blockIdx.x;
  int b = g & 127;
  int cc = g >> 7;               // 0..7
  int which = cc >> 2, chunk = cc & 3;
  int tchunk = which ? 50 : 64;
  int t0 = chunk * tchunk;
  const float* src = which ? (cenc + (size_t)b * T_CTX * H_DIM) : (enc + (size_t)b * T_ENC * H_DIM);
  const float* decp = decbuf + b * 1024 + which * 512;
  int tid = threadIdx.x, lane = tid & 63, wid = tid >> 6;
  float4 d0 = *(const float4*)(decp + lane * 8);
  float4 d1 = *(const float4*)(decp + lane * 8 + 4);
  float m = -1e30f, l = 0.f;
  float4 o0 = {0.f, 0.f, 0.f, 0.f}, o1 = {0.f, 0.f, 0.f, 0.f};
  for (int t = t0 + wid; t < t0 + tchunk; t += 4) {
    const float* row = src + (size_t)t * H_DIM + lane * 8;
    float4 r0 = *(const float4*)row;
    float4 r1 = *(const float4*)(row + 4);
    float p = r0.x * d0.x + r0.y * d0.y + r0.z * d0.z + r0.w * d0.w +
              r1.x * d1.x + r1.y * d1.y + r1.z * d1.z + r1.w * d1.w;
    p = wave_sum(p);
    if (which && lane == 0) rawsc[b * T_CTX + t] = p;
    float mn = fmaxf(m, p);
    float sc = __expf(m - mn);
    float e  = __expf(p - mn);
    l = l * sc + e;
    o0.x = o0.x * sc + e * r0.x; o0.y = o0.y * sc + e * r0.y;
    o0.z = o0.z * sc + e * r0.z; o0.w = o0.w * sc + e * r0.w;
    o1.x = o1.x * sc + e * r1.x; o1.y = o1.y * sc + e * r1.y;
    o1.z = o1.z * sc + e * r1.z; o1.w = o1.w * sc + e * r1.w;
    m = mn;
  }
  *(float4*)&so[wid][lane * 8]     = o0;
  *(float4*)&so[wid][lane * 8 + 4] = o1;
  if (lane == 0) { sml[wid][0] = m; sml[wid][1] = l; }
  __syncthreads();
  float M = fmaxf(fmaxf(sml[0][0], sml[1][0]), fmaxf(sml[2][0], sml[3][0]));
  float w0 = __expf(sml[0][0] - M), w1 = __expf(sml[1][0] - M);
  float w2 = __expf(sml[2][0] - M), w3 = __expf(sml[3][0] - M);
  float L = w0 * sml[0][1] + w1 * sml[1][1] + w2 * sml[2][1] + w3 * sml[3][1];
  int h = tid, h2 = tid + 256;
  float O0 = w0 * so[0][h]  + w1 * so[1][h]  + w2 * so[2][h]  + w3 * so[3][h];
  float O1 = w0 * so[0][h2] + w1 * so[1][h2] + w2 * so[2][h2] + w3 * so[3][h2];
  opart[(size_t)g * 512 + h]  = O0;
  opart[(size_t)g * 512 + h2] = O1;
  if (tid == 0) mlb[g] = make_float2(M, L);
}

// ---------------- final: combine everything + write logp ----------------
// Per block (c,b): attn-combine weights from mlb, p_gen from opart/h1/emb,
// row softmax stats from mspart, copy-prob scatter, logp transform.
__global__ __launch_bounds__(256) void final_kernel(
    const float* __restrict__ logits, size_t lpitch,
    float* __restrict__ out, const int* __restrict__ ctx_inp,
    const float* __restrict__ rawsc, const float2* __restrict__ mlb,
    const float2* __restrict__ mspart, const float* __restrict__ opart,
    const float* __restrict__ h1f, const float* __restrict__ embf,
    const float* __restrict__ genW, const float* __restrict__ genb,
    const float* __restrict__ sigb) {
  __shared__ float pc[VCHUNK];
  __shared__ float sm[256], ss[256];
  __shared__ float red8[8];
  int bx = blockIdx.x;           // c*128 + b
  int b = bx & 127, c = bx >> 7;
  int tid = threadIdx.x, lane = tid & 63, wid = tid >> 6;
  int cidx = (tid < T_CTX) ? ctx_inp[b * T_CTX + tid] : 0;

  // attention chunk-combine weights
  float2 e0 = mlb[b], e1 = mlb[128 + b], e2 = mlb[256 + b], e3 = mlb[384 + b];        // which=0
  float2 f0 = mlb[512 + b], f1 = mlb[640 + b], f2 = mlb[768 + b], f3 = mlb[896 + b];  // which=1
  float M0 = fmaxf(fmaxf(e0.x, e1.x), fmaxf(e2.x, e3.x));
  float a0 = __expf(e0.x - M0), a1 = __expf(e1.x - M0), a2 = __expf(e2.x - M0), a3 = __expf(e3.x - M0);
  float L0 = a0 * e0.y + a1 * e1.y + a2 * e2.y + a3 * e3.y;
  float M1 = fmaxf(fmaxf(f0.x, f1.x), fmaxf(f2.x, f3.x));
  float c0_ = __expf(f0.x - M1), c1_ = __expf(f1.x - M1), c2_ = __expf(f2.x - M1), c3_ = __expf(f3.x - M1);
  float L1 = c0_ * f0.y + c1_ * f1.y + c2_ * f2.y + c3_ * f3.y;

  // p_gen dot: feats = [ctx, cctx, h1, emb] . genW
  float acc = 0.f;
  for (int j = tid; j < 1792; j += 256) {
    float x;
    if (j < 1024) {
      int which = j >> 9, h = j & 511;
      const float* op = opart + ((size_t)(which * 512 + b) * 512) + h;
      if (which == 0)
        x = (a0 * op[0] + a1 * op[128 * 512] + a2 * op[256 * 512] + a3 * op[384 * 512]) / L0;
      else
        x = (c0_ * op[0] + c1_ * op[128 * 512] + c2_ * op[256 * 512] + c3_ * op[384 * 512]) / L1;
    } else if (j < 1536) x = h1f[b * 512 + j - 1024];
    else x = embf[b * 256 + j - 1536];
    acc += x * genW[j];
  }
  float cnt = (tid < T_CTX && cidx > 0) ? 1.f : 0.f;
  acc = wave_sum(acc); cnt = wave_sum(cnt);
  if (lane == 0) { red8[wid] = acc; red8[4 + wid] = cnt; }

  // row softmax stats from 782 per-block partials
  float m = -1e30f, s = 0.f;
  for (int cb = tid; cb < NBIG; cb += 256) {
    float2 p = mspart[(size_t)b * MSP_PITCH + cb];
    float mo = fmaxf(m, p.x);
    s = s * __expf(m - mo) + p.y * __expf(p.x - mo);
    m = mo;
  }
  sm[tid] = m; ss[tid] = s;
#pragma unroll
  for (int k = 0; k < 8; k++) pc[tid * 8 + k] = 0.f;
  __syncthreads();
  for (int st = 128; st; st >>= 1) {
    if (tid < st) {
      float m2 = sm[tid + st], s2 = ss[tid + st];
      float mo = fmaxf(sm[tid], m2);
      ss[tid] = ss[tid] * __expf(sm[tid] - mo) + s2 * __expf(m2 - mo);
      sm[tid] = mo;
    }
    __syncthreads();
  }
  float rm = sm[0], rs = ss[0];
  float pg;
  {
    float a = red8[0] + red8[1] + red8[2] + red8[3];
    float cn = red8[4] + red8[5] + red8[6] + red8[7];
    pg = sigm(a + genb[0] + sigb[0]);
    if (cn == 0.f) pg = 1.0f;
  }
  int v0c = c * VCHUNK;
  if (tid < T_CTX) {
    int rel = cidx - v0c;
    if (rel >= 0 && rel < VCHUNK) {
      float val = __expf(rawsc[b * T_CTX + tid] - M1) / L1;
      atomicAdd(&pc[rel], val);
    }
  }
  __syncthreads();
  float inv = 1.0f / rs, pc1 = 1.0f - pg;
  const float* rowsrc = logits + (size_t)b * lpitch;
  float* rowdst = out + (size_t)b * VEXT;
  int li0 = tid * 8;
#pragma unroll
  for (int k = 0; k < 4; k++) {
    int li = li0 + 2 * k;
    int v = v0c + li;
    float2 x = *(const float2*)(rowsrc + v);   // in-bounds of buffer; garbage past V_DIM guarded below
    float pv0 = (v < V_DIM)     ? __expf(x.x - rm) * inv : 0.f;
    float pv1 = (v + 1 < V_DIM) ? __expf(x.y - rm) * inv : 0.f;
    float r0 = __logf(fmaxf(pg * pv0 + pc1 * pc[li],     1e-10f));
    float r1 = __logf(fmaxf(pg * pv1 + pc1 * pc[li + 1], 1e-10f));
    if (v + 1 < VEXT)      *(float2*)(rowdst + v) = make_float2(r0, r1);
    else if (v < VEXT)     rowdst[v] = r0;
  }
}

extern "C" void kernel_launch(void* const* d_in, const int* in_sizes, int n_in,
                              void* d_out, int out_size, void* d_ws, size_t ws_size,
                              hipStream_t stream) {
  const int*   input   = (const int*)d_in[0];
  const float* h0      = (const float*)d_in[1];
  const float* c0      = (const float*)d_in[2];
  const float* enc     = (const float*)d_in[3];
  const float* cenc    = (const float*)d_in[4];
  const int*   ctx_inp = (const int*)d_in[5];
  const float* embT    = (const float*)d_in[6];
  const float* W_ih    = (const float*)d_in[7];
  const float* W_hh    = (const float*)d_in[8];
  const float* b_ih    = (const float*)d_in[9];
  const float* b_hh    = (const float*)d_in[10];
  const float* attnW   = (const float*)d_in[11];
  const float* attnb   = (const float*)d_in[12];
  const float* cattnW  = (const float*)d_in[13];
  const float* cattnb  = (const float*)d_in[14];
  const float* genW    = (const float*)d_in[15];
  const float* genb    = (const float*)d_in[16];
  const float* sigb    = (const float*)d_in[17];
  const float* outW    = (const float*)d_in[18];
  const float* outb    = (const float*)d_in[19];

  char* ws = (char*)d_ws;
  __bf16* Wcat   = (__bf16*)(ws + 0);            // 3145728
  __bf16* Wattn  = (__bf16*)(ws + 3145728);      // 1048576 -> 4194304
  float*  attnbc = (float*)(ws + 4194304);       // 4096    -> 4198400
  __bf16* Abuf   = (__bf16*)(ws + 4198400);      // 196608  -> 4395008
  float*  embf   = (float*)(ws + 4395008);       // 131072  -> 4526080
  float*  gates  = (float*)(ws + 4526080);       // 1048576 -> 5574656
  float*  gates2 = (float*)(ws + 5574656);       // 1048576 -> 6623232
  __bf16* h1b    = (__bf16*)(ws + 6623232);      // 131072  -> 6754304
  float*  decbuf = (float*)(ws + 6754304);       // 524288  -> 7278592
  float*  opart  = (float*)(ws + 7278592);       // 2097152 -> 9375744
  float2* mlb    = (float2*)(ws + 9375744);      // 8192    -> 9383936
  float*  rawsc  = (float*)(ws + 9383936);       // 102400  -> 9486336
  float2* mspart = (float2*)(ws + 9486336);      // 128*784*8 = 802816 -> 10289152
  const size_t logits_off = 10289152;
  const size_t LPITCH_AL = 50176;                // 64B-aligned row pitch

  // use an aligned scratch logits buffer if the workspace is big enough,
  // else fall back to in-place in d_out (pitch VEXT, misaligned rows)
  float* outF = (float*)d_out;
  bool padded = ws_size >= logits_off + (size_t)BB * LPITCH_AL * 4;
  float* logits = padded ? (float*)(ws + logits_off) : outF;
  size_t lpitch = padded ? LPITCH_AL : (size_t)VEXT;

  float* h1_out = outF + OUT_H1_OFF;
  float* c1_out = outF + OUT_C1_OFF;

  prep_all<<<2176, 256, 0, stream>>>(W_ih, W_hh, attnW, cattnW, attnb, cattnb,
                                     input, embT, h0, Wcat, Wattn, attnbc, Abuf, embf);
  gates_gemm<<<64, 256, 0, stream>>>(Abuf, Wcat, gates, gates2);
  lstm_kernel<<<256, 256, 0, stream>>>(gates, gates2, b_ih, b_hh, c0, h1_out, c1_out, h1b);
  mega_gemm<<<NBIG + 16, 256, 0, stream>>>(h1b, outW, outb, logits, lpitch,
                                           Wattn, attnbc, decbuf, mspart);
  flash_kernel<<<1024, 256, 0, stream>>>(enc, cenc, decbuf, opart, mlb, rawsc);
  final_kernel<<<NCHUNK * 128, 256, 0, stream>>>(logits, lpitch, outF, ctx_inp, rawsc, mlb,
                                                 mspart, opart, h1_out, embf, genW, genb, sigb);
}